// Round 2
// baseline (1770.350 us; speedup 1.0000x reference)
//
#include <hip/hip_runtime.h>
#include <hip/hip_bf16.h>
#include <math.h>

// Buggy flash-attn fwd: acc += (exp(qk*s - m_run) / l_run) @ V per 64-wide KV
// block, with running m/l exactly as the reference (no acc rescale).
// B=2 H=16 S=4096 D=128, fp32 in/out, bf16 MFMA compute.
// Round 2: V path rewritten as explicit V^T in LDS (no ds_read_b64_tr_b16,
// no inline asm) to bisect the round-1 correctness failure.

typedef __attribute__((ext_vector_type(8)))  unsigned short ushort8;
typedef __attribute__((ext_vector_type(8)))  __bf16        bf16x8;
typedef __attribute__((ext_vector_type(4)))  float         f32x4;
typedef __attribute__((ext_vector_type(4)))  float         floatv4;

#define SQ   4096
#define SKV  4096
#define DH   128
#define BN   64
#define QB   64
#define KLD  136   // K LDS row stride (bf16 elems): 128 + 8 pad
#define PLD  72    // P LDS row stride: 64 + 8 pad (144B, 16B-aligned rows)
#define VTLD 72    // Vt row stride (bf16 elems): 144B rows, 16B-aligned

static __device__ __forceinline__ unsigned short f2bf(float x) {
    unsigned u = __builtin_bit_cast(unsigned, x);
    u = (u + 0x7fffu + ((u >> 16) & 1u)) >> 16;  // round-to-nearest-even
    return (unsigned short)u;
}

__global__ __launch_bounds__(256) void fa_fwd_buggy(
    const float* __restrict__ Qg, const float* __restrict__ Kg,
    const float* __restrict__ Vg, float* __restrict__ Og)
{
    // LDS: K [64][136] (17.4KB), Vt [128][72] (18.4KB), P [64][72] (9.2KB).
    // Total 45KB -> 3 WGs/CU by LDS.
    __shared__ unsigned short K_lds[64 * KLD];
    __shared__ unsigned short Vt_lds[128 * VTLD];
    __shared__ unsigned short P_lds[64 * PLD];

    const int tid  = threadIdx.x;
    const int w    = tid >> 6;      // wave 0..3, owns q rows w*16..w*16+15
    const int lane = tid & 63;
    const int c    = lane & 15;
    const int g    = lane >> 4;

    const int bh    = blockIdx.y;
    const int qbase = blockIdx.x * QB;
    const float sm_scale = 0.08838834764831845f;  // 1/sqrt(128)

    // ---- Q A-fragments in registers: A row m = c, k = dc*32 + g*8 + j ----
    const float* Qrow = Qg + ((size_t)bh * SQ + qbase + w * 16 + c) * DH;
    ushort8 qf[4];
    #pragma unroll
    for (int dc = 0; dc < 4; ++dc) {
        floatv4 a = *(const floatv4*)(Qrow + dc * 32 + g * 8);
        floatv4 b = *(const floatv4*)(Qrow + dc * 32 + g * 8 + 4);
        ushort8 f;
        f[0]=f2bf(a[0]); f[1]=f2bf(a[1]); f[2]=f2bf(a[2]); f[3]=f2bf(a[3]);
        f[4]=f2bf(b[0]); f[5]=f2bf(b[1]); f[6]=f2bf(b[2]); f[7]=f2bf(b[3]);
        qf[dc] = f;
    }

    f32x4 acc[8];
    #pragma unroll
    for (int i = 0; i < 8; ++i) { f32x4 z = {0.f, 0.f, 0.f, 0.f}; acc[i] = z; }
    float m_run[4] = {-INFINITY, -INFINITY, -INFINITY, -INFINITY};
    float l_run[4] = {0.f, 0.f, 0.f, 0.f};

    const float* Kbh = Kg + (size_t)bh * SKV * DH;
    const float* Vbh = Vg + (size_t)bh * SKV * DH;

    for (int n0 = 0; n0 < SKV; n0 += BN) {
        __syncthreads();  // previous iter's LDS reads done before restage

        // ---- stage K (row-major bf16): thread covers (n, d0=8*cc) ----
        #pragma unroll
        for (int i = 0; i < 4; ++i) {
            const int grp = i * 256 + tid;
            const int n   = grp >> 4;
            const int d0  = (grp & 15) * 8;
            const float* ks = Kbh + (size_t)(n0 + n) * DH + d0;
            floatv4 a = *(const floatv4*)ks;
            floatv4 b = *(const floatv4*)(ks + 4);
            ushort8 f;
            f[0]=f2bf(a[0]); f[1]=f2bf(a[1]); f[2]=f2bf(a[2]); f[3]=f2bf(a[3]);
            f[4]=f2bf(b[0]); f[5]=f2bf(b[1]); f[6]=f2bf(b[2]); f[7]=f2bf(b[3]);
            *(ushort8*)&K_lds[n * KLD + d0] = f;
        }

        // ---- stage V transposed: Vt[d][n] = V[n0+n][d], d-interleaved so the
        // scalar ds_write_b16 banks spread (4c'+n/2 -> ~2-way) ----
        #pragma unroll
        for (int i = 0; i < 4; ++i) {
            const int grp = i * 256 + tid;
            const int n   = grp >> 4;     // 0..63
            const int cc  = grp & 15;     // 0..15
            const float* vs = Vbh + (size_t)(n0 + n) * DH + cc;
            #pragma unroll
            for (int jj = 0; jj < 8; ++jj) {
                Vt_lds[(cc + jj * 16) * VTLD + n] = f2bf(vs[jj * 16]);
            }
        }
        __syncthreads();

        // ---- S = Q K^T : 4 n-subtiles x 4 k-chunks of 16x16x32 MFMA ----
        // D layout (m89): col = c (kv index), row = 4g + r (q row)
        f32x4 s[4];
        #pragma unroll
        for (int ns = 0; ns < 4; ++ns) {
            f32x4 t = {0.f, 0.f, 0.f, 0.f};
            #pragma unroll
            for (int dc = 0; dc < 4; ++dc) {
                ushort8 kf = *(const ushort8*)&K_lds[(ns * 16 + c) * KLD + dc * 32 + g * 8];
                t = __builtin_amdgcn_mfma_f32_16x16x32_bf16(
                        __builtin_bit_cast(bf16x8, qf[dc]),
                        __builtin_bit_cast(bf16x8, kf), t, 0, 0, 0);
            }
            s[ns] = t;
        }

        // ---- online softmax, buggy variant (divide by running l, no rescale) ----
        #pragma unroll
        for (int r = 0; r < 4; ++r) {
            float mx = fmaxf(fmaxf(s[0][r], s[1][r]), fmaxf(s[2][r], s[3][r]));
            mx = fmaxf(mx, __shfl_xor(mx, 1));
            mx = fmaxf(mx, __shfl_xor(mx, 2));
            mx = fmaxf(mx, __shfl_xor(mx, 4));
            mx = fmaxf(mx, __shfl_xor(mx, 8));
            const float mc = fmaxf(mx * sm_scale, m_run[r]);
            float p0 = expf(fmaf(s[0][r], sm_scale, -mc));
            float p1 = expf(fmaf(s[1][r], sm_scale, -mc));
            float p2 = expf(fmaf(s[2][r], sm_scale, -mc));
            float p3 = expf(fmaf(s[3][r], sm_scale, -mc));
            float ps = p0 + p1 + p2 + p3;
            ps += __shfl_xor(ps, 1);
            ps += __shfl_xor(ps, 2);
            ps += __shfl_xor(ps, 4);
            ps += __shfl_xor(ps, 8);
            const float ln = l_run[r] * expf(m_run[r] - mc) + ps;  // exp(-inf)=0 on iter 0
            m_run[r] = mc;
            l_run[r] = ln;
            const float inv = 1.0f / ln;
            unsigned short* prow = &P_lds[(w * 16 + g * 4 + r) * PLD + c];
            prow[0]  = f2bf(p0 * inv);
            prow[16] = f2bf(p1 * inv);
            prow[32] = f2bf(p2 * inv);
            prow[48] = f2bf(p3 * inv);
        }

        // Same-wave cross-lane RAW through P_lds: DS pipe is in-order per wave;
        // the memory-clobber waitcnt pins program order as cheap insurance.
        asm volatile("s_waitcnt lgkmcnt(0)" ::: "memory");

        // ---- P A-fragments: A row m = c, k(=kv n) = chunk*32 + g*8 + j ----
        ushort8 pa0 = *(const ushort8*)&P_lds[(w * 16 + c) * PLD +  0 + g * 8];
        ushort8 pa1 = *(const ushort8*)&P_lds[(w * 16 + c) * PLD + 32 + g * 8];

        // ---- PV: B-frag from Vt rows: B[k=g*8+j][col d=dt*16+c] ----
        #pragma unroll
        for (int dt = 0; dt < 8; ++dt) {
            ushort8 vb0 = *(const ushort8*)&Vt_lds[(dt * 16 + c) * VTLD +  0 + g * 8];
            ushort8 vb1 = *(const ushort8*)&Vt_lds[(dt * 16 + c) * VTLD + 32 + g * 8];
            acc[dt] = __builtin_amdgcn_mfma_f32_16x16x32_bf16(
                __builtin_bit_cast(bf16x8, pa0), __builtin_bit_cast(bf16x8, vb0), acc[dt], 0,0,0);
            acc[dt] = __builtin_amdgcn_mfma_f32_16x16x32_bf16(
                __builtin_bit_cast(bf16x8, pa1), __builtin_bit_cast(bf16x8, vb1), acc[dt], 0,0,0);
        }
    }

    // ---- epilogue: row m = 4g + r, col d = dt*16 + c ----
    float* orow = Og + ((size_t)bh * SQ + qbase + w * 16 + g * 4) * DH + c;
    #pragma unroll
    for (int r = 0; r < 4; ++r) {
        #pragma unroll
        for (int dt = 0; dt < 8; ++dt)
            orow[(size_t)r * DH + dt * 16] = acc[dt][r];
    }
}

extern "C" void kernel_launch(void* const* d_in, const int* in_sizes, int n_in,
                              void* d_out, int out_size, void* d_ws, size_t ws_size,
                              hipStream_t stream) {
    const float* q = (const float*)d_in[0];
    const float* k = (const float*)d_in[1];
    const float* v = (const float*)d_in[2];
    float* o = (float*)d_out;
    const int BH = in_sizes[0] / (SQ * DH);  // 32
    dim3 grid(SQ / QB, BH);
    fa_fwd_buggy<<<grid, 256, 0, stream>>>(q, k, v, o);
}

// Round 3
// 995.243 us; speedup vs baseline: 1.7788x; 1.7788x over previous
//
#include <hip/hip_runtime.h>
#include <hip/hip_bf16.h>
#include <math.h>

// Buggy flash-attn fwd (no acc rescale, running-l division) per 64-wide KV
// block. B=2 H=16 S=4096 D=128, fp32 in/out, bf16 MFMA compute.
// Round 3: QB=128 / 8 waves, register-transposed+swizzled V staging (b64),
// T14 async-stage split (loads for t+2 issued under compute of t+1),
// exp2-domain softmax with scale baked into Q.

typedef __attribute__((ext_vector_type(8)))  unsigned short ushort8;
typedef __attribute__((ext_vector_type(8)))  __bf16        bf16x8;
typedef __attribute__((ext_vector_type(4)))  float         f32x4;
typedef __attribute__((ext_vector_type(4)))  float         floatv4;
typedef __attribute__((ext_vector_type(2)))  unsigned int  uint2v;

#define SQ   4096
#define SKV  4096
#define DH   128
#define BN   64
#define QB   128
#define NT   (SKV / BN)   // 64
#define KLD  136   // K LDS row stride (bf16 elems): 128 + 8 pad
#define PLD  72    // P LDS row stride: 64 + 8 (rows 16B-aligned for b128)
#define VTLD 72    // Vt row stride: 64 data + 8 pad, 8-unit XOR swizzled

static __device__ __forceinline__ unsigned short f2bf(float x) {
    unsigned u = __builtin_bit_cast(unsigned, x);
    u = (u + 0x7fffu + ((u >> 16) & 1u)) >> 16;  // RNE
    return (unsigned short)u;
}

__global__ __launch_bounds__(512, 4) void fa_fwd_buggy(
    const float* __restrict__ Qg, const float* __restrict__ Kg,
    const float* __restrict__ Vg, float* __restrict__ Og)
{
    // LDS: K 17.4KB + Vt 18.4KB + P 18.4KB = 54.2KB -> 2 blocks/CU (16 waves).
    __shared__ unsigned short K_lds[64 * KLD];
    __shared__ unsigned short Vt_lds[DH * VTLD];
    __shared__ unsigned short P_lds[QB * PLD];

    const int tid  = threadIdx.x;
    const int w    = tid >> 6;      // wave 0..7, owns q rows w*16..w*16+15
    const int lane = tid & 63;
    const int c    = lane & 15;
    const int g    = lane >> 4;

    const int bh    = blockIdx.y;
    const int qbase = blockIdx.x * QB;
    // sm_scale * log2(e): QK^T lands directly in exp2 domain.
    const float qscale = 0.08838834764831845f * 1.44269504088896341f;

    // ---- Q A-fragments, pre-scaled: A row m = c, k = dc*32 + g*8 + j ----
    const float* Qrow = Qg + ((size_t)bh * SQ + qbase + w * 16 + c) * DH;
    ushort8 qf[4];
    #pragma unroll
    for (int dc = 0; dc < 4; ++dc) {
        floatv4 a = *(const floatv4*)(Qrow + dc * 32 + g * 8);
        floatv4 b = *(const floatv4*)(Qrow + dc * 32 + g * 8 + 4);
        ushort8 f;
        f[0]=f2bf(a[0]*qscale); f[1]=f2bf(a[1]*qscale);
        f[2]=f2bf(a[2]*qscale); f[3]=f2bf(a[3]*qscale);
        f[4]=f2bf(b[0]*qscale); f[5]=f2bf(b[1]*qscale);
        f[6]=f2bf(b[2]*qscale); f[7]=f2bf(b[3]*qscale);
        qf[dc] = f;
    }

    f32x4 acc[8];
    #pragma unroll
    for (int i = 0; i < 8; ++i) { f32x4 z = {0.f,0.f,0.f,0.f}; acc[i] = z; }
    float m2[4] = {-INFINITY, -INFINITY, -INFINITY, -INFINITY};  // log2 domain
    float l_run[4] = {0.f, 0.f, 0.f, 0.f};

    const float* Kbh = Kg + (size_t)bh * SKV * DH;
    const float* Vbh = Vg + (size_t)bh * SKV * DH;

    // staging thread mappings (512 threads, 16 elems each for K and V)
    const int n_k = tid >> 3;          // K row 0..63
    const int u_k = tid & 7;           // K 8-elem units {u_k, u_k+8}
    const int dq  = tid & 31;          // V d-block (d = 4*dq)
    const int nq  = tid >> 5;          // V n-block 0..15 (n = 4*nq)
    const int vswz = (dq >> 1) & 7;    // (d>>3)&7, const over i

    floatv4 ka0, ka1, kb0, kb1;        // K stage regs (named: rule #20)
    floatv4 va0, va1, va2, va3;        // V stage regs (4 rows x float4)

#define LOAD_TILE(N0) do {                                                   \
        const float* ks_ = Kbh + (size_t)((N0) + n_k) * DH + u_k * 8;        \
        ka0 = *(const floatv4*)(ks_);        ka1 = *(const floatv4*)(ks_+4); \
        kb0 = *(const floatv4*)(ks_ + 64);   kb1 = *(const floatv4*)(ks_+68);\
        const float* vs_ = Vbh + (size_t)((N0) + nq * 4) * DH + dq * 4;      \
        va0 = *(const floatv4*)(vs_);        va1 = *(const floatv4*)(vs_+DH);\
        va2 = *(const floatv4*)(vs_+2*DH);   va3 = *(const floatv4*)(vs_+3*DH);\
    } while (0)

#define STORE_TILE() do {                                                    \
        ushort8 f_;                                                          \
        f_[0]=f2bf(ka0[0]); f_[1]=f2bf(ka0[1]); f_[2]=f2bf(ka0[2]);          \
        f_[3]=f2bf(ka0[3]); f_[4]=f2bf(ka1[0]); f_[5]=f2bf(ka1[1]);          \
        f_[6]=f2bf(ka1[2]); f_[7]=f2bf(ka1[3]);                              \
        *(ushort8*)&K_lds[n_k * KLD + u_k * 8] = f_;                         \
        f_[0]=f2bf(kb0[0]); f_[1]=f2bf(kb0[1]); f_[2]=f2bf(kb0[2]);          \
        f_[3]=f2bf(kb0[3]); f_[4]=f2bf(kb1[0]); f_[5]=f2bf(kb1[1]);          \
        f_[6]=f2bf(kb1[2]); f_[7]=f2bf(kb1[3]);                              \
        *(ushort8*)&K_lds[n_k * KLD + (u_k + 8) * 8] = f_;                   \
        _Pragma("unroll")                                                    \
        for (int i_ = 0; i_ < 4; ++i_) {                                     \
            const int d_ = dq * 4 + i_;                                      \
            uint2v p_;                                                       \
            p_[0] = (unsigned)f2bf(va0[i_]) | ((unsigned)f2bf(va1[i_])<<16); \
            p_[1] = (unsigned)f2bf(va2[i_]) | ((unsigned)f2bf(va3[i_])<<16); \
            const int unit_ = (nq >> 1) ^ vswz;                              \
            *(uint2v*)&Vt_lds[d_ * VTLD + unit_ * 8 + (nq & 1) * 4] = p_;    \
        }                                                                    \
    } while (0)

    // prologue: tile 0 to LDS, tile 1 to regs
    LOAD_TILE(0);
    STORE_TILE();
    __syncthreads();
    LOAD_TILE(BN);

    for (int t = 0; t < NT; ++t) {
        // ---- S = Q K^T (exp2 domain): D col = c (kv), row = 4g + r (q) ----
        f32x4 s[4];
        #pragma unroll
        for (int ns = 0; ns < 4; ++ns) {
            f32x4 tt = {0.f,0.f,0.f,0.f};
            #pragma unroll
            for (int dc = 0; dc < 4; ++dc) {
                ushort8 kf = *(const ushort8*)&K_lds[(ns * 16 + c) * KLD + dc * 32 + g * 8];
                tt = __builtin_amdgcn_mfma_f32_16x16x32_bf16(
                        __builtin_bit_cast(bf16x8, qf[dc]),
                        __builtin_bit_cast(bf16x8, kf), tt, 0, 0, 0);
            }
            s[ns] = tt;
        }

        // ---- online softmax (buggy variant), exp2 domain ----
        #pragma unroll
        for (int r = 0; r < 4; ++r) {
            float mx = fmaxf(fmaxf(s[0][r], s[1][r]), fmaxf(s[2][r], s[3][r]));
            mx = fmaxf(mx, __shfl_xor(mx, 1));
            mx = fmaxf(mx, __shfl_xor(mx, 2));
            mx = fmaxf(mx, __shfl_xor(mx, 4));
            mx = fmaxf(mx, __shfl_xor(mx, 8));
            const float mc = fmaxf(mx, m2[r]);
            float p0 = exp2f(s[0][r] - mc);
            float p1 = exp2f(s[1][r] - mc);
            float p2 = exp2f(s[2][r] - mc);
            float p3 = exp2f(s[3][r] - mc);
            float ps = p0 + p1 + p2 + p3;
            ps += __shfl_xor(ps, 1);
            ps += __shfl_xor(ps, 2);
            ps += __shfl_xor(ps, 4);
            ps += __shfl_xor(ps, 8);
            const float ln = l_run[r] * exp2f(m2[r] - mc) + ps;
            m2[r] = mc;
            l_run[r] = ln;
            const float inv = __builtin_amdgcn_rcpf(ln);
            unsigned short* prow = &P_lds[(w * 16 + g * 4 + r) * PLD + c];
            prow[0]  = f2bf(p0 * inv);
            prow[16] = f2bf(p1 * inv);
            prow[32] = f2bf(p2 * inv);
            prow[48] = f2bf(p3 * inv);
        }

        // same-wave RAW through P_lds (DS in-order per wave; pin as insurance)
        asm volatile("s_waitcnt lgkmcnt(0)" ::: "memory");

        ushort8 pa0 = *(const ushort8*)&P_lds[(w * 16 + c) * PLD +  0 + g * 8];
        ushort8 pa1 = *(const ushort8*)&P_lds[(w * 16 + c) * PLD + 32 + g * 8];

        // ---- PV: B[k = nc*32+g*8+j][d = dt*16+c] from swizzled Vt ----
        #pragma unroll
        for (int dt = 0; dt < 8; ++dt) {
            const int d  = dt * 16 + c;
            const int fz = (d >> 3) & 7;
            ushort8 vb0 = *(const ushort8*)&Vt_lds[d * VTLD + ((0 + g) ^ fz) * 8];
            ushort8 vb1 = *(const ushort8*)&Vt_lds[d * VTLD + ((4 + g) ^ fz) * 8];
            acc[dt] = __builtin_amdgcn_mfma_f32_16x16x32_bf16(
                __builtin_bit_cast(bf16x8, pa0), __builtin_bit_cast(bf16x8, vb0), acc[dt], 0,0,0);
            acc[dt] = __builtin_amdgcn_mfma_f32_16x16x32_bf16(
                __builtin_bit_cast(bf16x8, pa1), __builtin_bit_cast(bf16x8, vb1), acc[dt], 0,0,0);
        }

        __syncthreads();               // all reads of tile t complete
        if (t + 1 < NT) {
            STORE_TILE();              // regs (tile t+1) -> LDS
            if (t + 2 < NT) LOAD_TILE((size_t)(t + 2) * BN);  // hide under next compute
            __syncthreads();           // writes visible
        }
    }

    // ---- epilogue: row m = 4g + r, col d = dt*16 + c ----
    float* orow = Og + ((size_t)bh * SQ + qbase + w * 16 + g * 4) * DH + c;
    #pragma unroll
    for (int r = 0; r < 4; ++r) {
        #pragma unroll
        for (int dt = 0; dt < 8; ++dt)
            orow[(size_t)r * DH + dt * 16] = acc[dt][r];
    }
}

extern "C" void kernel_launch(void* const* d_in, const int* in_sizes, int n_in,
                              void* d_out, int out_size, void* d_ws, size_t ws_size,
                              hipStream_t stream) {
    const float* q = (const float*)d_in[0];
    const float* k = (const float*)d_in[1];
    const float* v = (const float*)d_in[2];
    float* o = (float*)d_out;
    dim3 grid(SQ / QB, 32);
    fa_fwd_buggy<<<grid, 512, 0, stream>>>(q, k, v, o);
}

// Round 4
// 500.357 us; speedup vs baseline: 3.5382x; 1.9891x over previous
//
#include <hip/hip_runtime.h>
#include <hip/hip_bf16.h>
#include <math.h>

// Buggy flash-attn fwd (no acc rescale, running-l division) per 64-wide KV
// block. B=2 H=16 S=4096 D=128, fp32 in/out, bf16 MFMA compute.
// Round 4: swapped QK^T (mfma(K,Q)) -> P stays in registers, redistributed to
// PV A-frags via cvt_pk + 16x ds_bpermute (P_lds deleted); bh->XCD grouping
// for K/V L2 locality; hardware bf16 converts; setprio around MFMA.

typedef __attribute__((ext_vector_type(8)))  unsigned short ushort8;
typedef __attribute__((ext_vector_type(8)))  __bf16        bf16x8;
typedef __attribute__((ext_vector_type(4)))  float         f32x4;
typedef __attribute__((ext_vector_type(4)))  float         floatv4;
typedef __attribute__((ext_vector_type(2)))  unsigned int  uint2v;
typedef __attribute__((ext_vector_type(4)))  unsigned int  uint4v;

#define SQ   4096
#define SKV  4096
#define DH   128
#define BN   64
#define QB   128
#define NT   (SKV / BN)   // 64
#define KLD  136   // K LDS row stride (bf16 elems): 128 + 8 pad
#define VTLD 72    // Vt row stride: 64 data + 8 pad, 8-unit XOR swizzled

static __device__ __forceinline__ unsigned short f2bf(float x) {
    return __builtin_bit_cast(unsigned short, __float2bfloat16(x));  // RNE, HW cvt
}
static __device__ __forceinline__ unsigned pk2(float lo, float hi) {
    return (unsigned)f2bf(lo) | ((unsigned)f2bf(hi) << 16);  // fuses to v_cvt_pk_bf16_f32
}

__global__ __launch_bounds__(512, 4) void fa_fwd_buggy(
    const float* __restrict__ Qg, const float* __restrict__ Kg,
    const float* __restrict__ Vg, float* __restrict__ Og)
{
    // LDS: K 17.4KB + Vt 18.4KB = 35KB -> 4 WG/CU (occupancy now VGPR-capped).
    __shared__ unsigned short K_lds[64 * KLD];
    __shared__ unsigned short Vt_lds[DH * VTLD];

    const int tid  = threadIdx.x;
    const int w    = tid >> 6;      // wave 0..7, owns q rows w*16..w*16+15
    const int lane = tid & 63;
    const int c    = lane & 15;
    const int g    = lane >> 4;

    // bh->XCD grouping: all 32 qtiles of one bh on one XCD (wgid%8 assumption;
    // worst case it's just a different bijective order).
    const int wgid  = blockIdx.x;
    const int bh    = (wgid & 7) * 4 + (wgid >> 8);
    const int qtile = (wgid >> 3) & 31;
    const int qbase = qtile * QB;
    // sm_scale * log2(e): QK^T lands directly in exp2 domain.
    const float qscale = 0.08838834764831845f * 1.44269504088896341f;

    // ---- Q fragments (B-operand now): n = c = q-row, k = dc*32 + g*8 + j ----
    const float* Qrow = Qg + ((size_t)bh * SQ + qbase + w * 16 + c) * DH;
    ushort8 qf[4];
    #pragma unroll
    for (int dc = 0; dc < 4; ++dc) {
        floatv4 a = *(const floatv4*)(Qrow + dc * 32 + g * 8);
        floatv4 b = *(const floatv4*)(Qrow + dc * 32 + g * 8 + 4);
        uint4v u;
        u[0] = pk2(a[0]*qscale, a[1]*qscale);
        u[1] = pk2(a[2]*qscale, a[3]*qscale);
        u[2] = pk2(b[0]*qscale, b[1]*qscale);
        u[3] = pk2(b[2]*qscale, b[3]*qscale);
        qf[dc] = __builtin_bit_cast(ushort8, u);
    }

    f32x4 acc[8];
    #pragma unroll
    for (int i = 0; i < 8; ++i) { f32x4 z = {0.f,0.f,0.f,0.f}; acc[i] = z; }
    // per-lane running stats for q-row = c (lanes c,c+16,c+32,c+48 duplicate)
    float m2 = -INFINITY;   // log2 domain
    float l_run = 0.f;

    const float* Kbh = Kg + (size_t)bh * SKV * DH;
    const float* Vbh = Vg + (size_t)bh * SKV * DH;

    // staging thread mappings (512 threads)
    const int n_k = tid >> 3;          // K row 0..63
    const int u_k = tid & 7;           // K 8-elem units {u_k, u_k+8}
    const int dq  = tid & 31;          // V d-block (d = 4*dq)
    const int nq  = tid >> 5;          // V n-block 0..15 (n = 4*nq)
    const int vswz = (dq >> 1) & 7;    // (d>>3)&7

    floatv4 ka0, ka1, kb0, kb1;        // K stage regs
    floatv4 va0, va1, va2, va3;        // V stage regs

#define LOAD_TILE(N0) do {                                                   \
        const float* ks_ = Kbh + (size_t)((N0) + n_k) * DH + u_k * 8;        \
        ka0 = *(const floatv4*)(ks_);        ka1 = *(const floatv4*)(ks_+4); \
        kb0 = *(const floatv4*)(ks_ + 64);   kb1 = *(const floatv4*)(ks_+68);\
        const float* vs_ = Vbh + (size_t)((N0) + nq * 4) * DH + dq * 4;      \
        va0 = *(const floatv4*)(vs_);        va1 = *(const floatv4*)(vs_+DH);\
        va2 = *(const floatv4*)(vs_+2*DH);   va3 = *(const floatv4*)(vs_+3*DH);\
    } while (0)

#define STORE_TILE() do {                                                    \
        uint4v u_;                                                           \
        u_[0]=pk2(ka0[0],ka0[1]); u_[1]=pk2(ka0[2],ka0[3]);                  \
        u_[2]=pk2(ka1[0],ka1[1]); u_[3]=pk2(ka1[2],ka1[3]);                  \
        *(uint4v*)&K_lds[n_k * KLD + u_k * 8] = u_;                          \
        u_[0]=pk2(kb0[0],kb0[1]); u_[1]=pk2(kb0[2],kb0[3]);                  \
        u_[2]=pk2(kb1[0],kb1[1]); u_[3]=pk2(kb1[2],kb1[3]);                  \
        *(uint4v*)&K_lds[n_k * KLD + (u_k + 8) * 8] = u_;                    \
        _Pragma("unroll")                                                    \
        for (int i_ = 0; i_ < 4; ++i_) {                                     \
            const int d_ = dq * 4 + i_;                                      \
            uint2v p_;                                                       \
            p_[0] = pk2(va0[i_], va1[i_]);                                   \
            p_[1] = pk2(va2[i_], va3[i_]);                                   \
            const int unit_ = (nq >> 1) ^ vswz;                              \
            *(uint2v*)&Vt_lds[d_ * VTLD + unit_ * 8 + (nq & 1) * 4] = p_;    \
        }                                                                    \
    } while (0)

    // prologue: tile 0 to LDS, tile 1 to regs
    LOAD_TILE(0);
    STORE_TILE();
    __syncthreads();
    LOAD_TILE(BN);

    // bpermute source-lane addresses (byte = lane*4), constant per thread:
    // srclane = c + 16*(2*(g&1) + (jp>>1))
    const int addr0 = (c + 16 * (2 * (g & 1))) * 4;
    const int addr1 = addr0 + 64;
    const bool hi_half = (g >> 1) != 0;

    for (int t = 0; t < NT; ++t) {
        // ---- S = K Q^T (swapped): lane (c,g) gets S[q=c][kv=16ns+4g+r] ----
        f32x4 s[4];
        __builtin_amdgcn_s_setprio(1);
        #pragma unroll
        for (int ns = 0; ns < 4; ++ns) {
            f32x4 tt = {0.f,0.f,0.f,0.f};
            #pragma unroll
            for (int dc = 0; dc < 4; ++dc) {
                ushort8 kf = *(const ushort8*)&K_lds[(ns * 16 + c) * KLD + dc * 32 + g * 8];
                tt = __builtin_amdgcn_mfma_f32_16x16x32_bf16(
                        __builtin_bit_cast(bf16x8, kf),
                        __builtin_bit_cast(bf16x8, qf[dc]), tt, 0, 0, 0);
            }
            s[ns] = tt;
        }
        __builtin_amdgcn_s_setprio(0);

        // ---- online softmax (buggy variant), exp2 domain, per-lane row q=c ----
        float mx = s[0][0];
        #pragma unroll
        for (int ns = 0; ns < 4; ++ns)
            #pragma unroll
            for (int r = 0; r < 4; ++r) mx = fmaxf(mx, s[ns][r]);
        mx = fmaxf(mx, __shfl_xor(mx, 16));
        mx = fmaxf(mx, __shfl_xor(mx, 32));
        const float mc = fmaxf(mx, m2);
        float p[4][4];
        float ps = 0.f;
        #pragma unroll
        for (int ns = 0; ns < 4; ++ns)
            #pragma unroll
            for (int r = 0; r < 4; ++r) {
                const float e = exp2f(s[ns][r] - mc);
                p[ns][r] = e;
                ps += e;
            }
        ps += __shfl_xor(ps, 16);
        ps += __shfl_xor(ps, 32);
        const float ln = l_run * exp2f(m2 - mc) + ps;
        m2 = mc;
        l_run = ln;
        const float inv = __builtin_amdgcn_rcpf(ln);

        // ---- pack P/l to bf16 words: wds[ns][rp] = (p[ns][2rp], p[ns][2rp+1]) ----
        unsigned wds[4][2];
        #pragma unroll
        for (int ns = 0; ns < 4; ++ns)
            #pragma unroll
            for (int rp = 0; rp < 2; ++rp)
                wds[ns][rp] = pk2(p[ns][2*rp] * inv, p[ns][2*rp+1] * inv);

        // ---- in-register redistribution to PV A-frags:
        // pa[kp] word jp <- wds[2kp + (g>>1)][jp&1] of lane c + 16*(2(g&1)+(jp>>1))
        uint4v paw0, paw1;
        #pragma unroll
        for (int jp = 0; jp < 4; ++jp) {
            const int adr = (jp >> 1) ? addr1 : addr0;
            const int rp  = jp & 1;
            int x0 = __builtin_amdgcn_ds_bpermute(adr, (int)wds[0][rp]);
            int y0 = __builtin_amdgcn_ds_bpermute(adr, (int)wds[1][rp]);
            int x1 = __builtin_amdgcn_ds_bpermute(adr, (int)wds[2][rp]);
            int y1 = __builtin_amdgcn_ds_bpermute(adr, (int)wds[3][rp]);
            paw0[jp] = (unsigned)(hi_half ? y0 : x0);
            paw1[jp] = (unsigned)(hi_half ? y1 : x1);
        }
        ushort8 pa0 = __builtin_bit_cast(ushort8, paw0);
        ushort8 pa1 = __builtin_bit_cast(ushort8, paw1);

        // ---- PV: B[k = kc*32+g*8+j][d = dt*16+c] from swizzled Vt ----
        __builtin_amdgcn_s_setprio(1);
        #pragma unroll
        for (int dt = 0; dt < 8; ++dt) {
            const int d  = dt * 16 + c;
            const int fz = (d >> 3) & 7;
            ushort8 vb0 = *(const ushort8*)&Vt_lds[d * VTLD + ((0 + g) ^ fz) * 8];
            ushort8 vb1 = *(const ushort8*)&Vt_lds[d * VTLD + ((4 + g) ^ fz) * 8];
            acc[dt] = __builtin_amdgcn_mfma_f32_16x16x32_bf16(
                __builtin_bit_cast(bf16x8, pa0), __builtin_bit_cast(bf16x8, vb0), acc[dt], 0,0,0);
            acc[dt] = __builtin_amdgcn_mfma_f32_16x16x32_bf16(
                __builtin_bit_cast(bf16x8, pa1), __builtin_bit_cast(bf16x8, vb1), acc[dt], 0,0,0);
        }
        __builtin_amdgcn_s_setprio(0);

        __syncthreads();               // all reads of tile t complete
        if (t + 1 < NT) {
            STORE_TILE();              // regs (tile t+1) -> LDS
            if (t + 2 < NT) LOAD_TILE((size_t)(t + 2) * BN);  // hide under compute
            __syncthreads();           // writes visible
        }
    }

    // ---- epilogue: row = 4g + r = q-row-in-wave, col d = dt*16 + c ----
    float* orow = Og + ((size_t)bh * SQ + qbase + w * 16 + g * 4) * DH + c;
    #pragma unroll
    for (int r = 0; r < 4; ++r) {
        #pragma unroll
        for (int dt = 0; dt < 8; ++dt)
            orow[(size_t)r * DH + dt * 16] = acc[dt][r];
    }
}

extern "C" void kernel_launch(void* const* d_in, const int* in_sizes, int n_in,
                              void* d_out, int out_size, void* d_ws, size_t ws_size,
                              hipStream_t stream) {
    const float* q = (const float*)d_in[0];
    const float* k = (const float*)d_in[1];
    const float* v = (const float*)d_in[2];
    float* o = (float*)d_out;
    dim3 grid(1024);
    fa_fwd_buggy<<<grid, 512, 0, stream>>>(q, k, v, o);
}

// Round 5
// 454.125 us; speedup vs baseline: 3.8984x; 1.1018x over previous
//
#include <hip/hip_runtime.h>
#include <hip/hip_bf16.h>
#include <math.h>

// Buggy flash-attn fwd (no acc rescale, running-l division) per 64-wide KV
// block. B=2 H=16 S=4096 D=128, fp32 in/out, bf16 MFMA compute.
// Round 5: double-buffered K/Vt LDS (one barrier per tile, store overlaps
// compute), packed bf16 converts via __builtin_convertvector, vestigial
// lgkmcnt removed. Swapped QK^T + in-register P via ds_bpermute (round 4).

typedef __attribute__((ext_vector_type(8)))  unsigned short ushort8;
typedef __attribute__((ext_vector_type(8)))  __bf16        bf16x8;
typedef __attribute__((ext_vector_type(2)))  __bf16        bf16x2;
typedef __attribute__((ext_vector_type(2)))  float         float2v;
typedef __attribute__((ext_vector_type(4)))  float         f32x4;
typedef __attribute__((ext_vector_type(4)))  float         floatv4;
typedef __attribute__((ext_vector_type(2)))  unsigned int  uint2v;
typedef __attribute__((ext_vector_type(4)))  unsigned int  uint4v;

#define SQ   4096
#define SKV  4096
#define DH   128
#define BN   64
#define QB   128
#define NT   (SKV / BN)   // 64
#define KLD  136   // K LDS row stride (bf16 elems): 128 + 8 pad
#define VTLD 72    // Vt row stride: 64 data + 8 pad, 8-unit XOR swizzled
#define KBUF (64 * KLD)
#define VBUF (DH * VTLD)

// packed f32x2 -> bf16x2 word (v_cvt_pk_bf16_f32, RNE)
static __device__ __forceinline__ unsigned pk2(float lo, float hi) {
    float2v f = {lo, hi};
    bf16x2 h = __builtin_convertvector(f, bf16x2);
    return __builtin_bit_cast(unsigned, h);
}

__global__ __launch_bounds__(512, 4) void fa_fwd_buggy(
    const float* __restrict__ Qg, const float* __restrict__ Kg,
    const float* __restrict__ Vg, float* __restrict__ Og)
{
    // LDS: 2 x (K 17.4KB + Vt 18.4KB) = 70KB. Residency is reg-capped at
    // 2 WG/CU (96 unified regs), so double-buffering is occupancy-free.
    __shared__ unsigned short K_lds[2 * KBUF];
    __shared__ unsigned short Vt_lds[2 * VBUF];

    const int tid  = threadIdx.x;
    const int w    = tid >> 6;      // wave 0..7, owns q rows w*16..w*16+15
    const int lane = tid & 63;
    const int c    = lane & 15;
    const int g    = lane >> 4;

    // bh->XCD grouping: all 32 qtiles of one bh on one XCD.
    const int wgid  = blockIdx.x;
    const int bh    = (wgid & 7) * 4 + (wgid >> 8);
    const int qtile = (wgid >> 3) & 31;
    const int qbase = qtile * QB;
    // sm_scale * log2(e): QK^T lands directly in exp2 domain.
    const float qscale = 0.08838834764831845f * 1.44269504088896341f;

    // ---- Q fragments (B-operand): n = c = q-row, k = dc*32 + g*8 + j ----
    const float* Qrow = Qg + ((size_t)bh * SQ + qbase + w * 16 + c) * DH;
    ushort8 qf[4];
    #pragma unroll
    for (int dc = 0; dc < 4; ++dc) {
        floatv4 a = *(const floatv4*)(Qrow + dc * 32 + g * 8);
        floatv4 b = *(const floatv4*)(Qrow + dc * 32 + g * 8 + 4);
        uint4v u;
        u[0] = pk2(a[0]*qscale, a[1]*qscale);
        u[1] = pk2(a[2]*qscale, a[3]*qscale);
        u[2] = pk2(b[0]*qscale, b[1]*qscale);
        u[3] = pk2(b[2]*qscale, b[3]*qscale);
        qf[dc] = __builtin_bit_cast(ushort8, u);
    }

    f32x4 acc[8];
    #pragma unroll
    for (int i = 0; i < 8; ++i) { f32x4 z = {0.f,0.f,0.f,0.f}; acc[i] = z; }
    // per-lane running stats for q-row = c (lanes c,c+16,c+32,c+48 duplicate)
    float m2 = -INFINITY;   // log2 domain
    float l_run = 0.f;

    const float* Kbh = Kg + (size_t)bh * SKV * DH;
    const float* Vbh = Vg + (size_t)bh * SKV * DH;

    // staging thread mappings (512 threads)
    const int n_k = tid >> 3;          // K row 0..63
    const int u_k = tid & 7;           // K 8-elem units {u_k, u_k+8}
    const int dq  = tid & 31;          // V d-block (d = 4*dq)
    const int nq  = tid >> 5;          // V n-block 0..15 (n = 4*nq)
    const int vswz = (dq >> 1) & 7;    // (d>>3)&7

    floatv4 ka0, ka1, kb0, kb1;        // K stage regs
    floatv4 va0, va1, va2, va3;        // V stage regs

#define LOAD_TILE(N0) do {                                                   \
        const float* ks_ = Kbh + (size_t)((N0) + n_k) * DH + u_k * 8;        \
        ka0 = *(const floatv4*)(ks_);        ka1 = *(const floatv4*)(ks_+4); \
        kb0 = *(const floatv4*)(ks_ + 64);   kb1 = *(const floatv4*)(ks_+68);\
        const float* vs_ = Vbh + (size_t)((N0) + nq * 4) * DH + dq * 4;      \
        va0 = *(const floatv4*)(vs_);        va1 = *(const floatv4*)(vs_+DH);\
        va2 = *(const floatv4*)(vs_+2*DH);   va3 = *(const floatv4*)(vs_+3*DH);\
    } while (0)

#define STORE_TILE(B) do {                                                   \
        unsigned short* kd_ = &K_lds[(B) * KBUF];                            \
        unsigned short* vd_ = &Vt_lds[(B) * VBUF];                           \
        uint4v u_;                                                           \
        u_[0]=pk2(ka0[0],ka0[1]); u_[1]=pk2(ka0[2],ka0[3]);                  \
        u_[2]=pk2(ka1[0],ka1[1]); u_[3]=pk2(ka1[2],ka1[3]);                  \
        *(uint4v*)&kd_[n_k * KLD + u_k * 8] = u_;                            \
        u_[0]=pk2(kb0[0],kb0[1]); u_[1]=pk2(kb0[2],kb0[3]);                  \
        u_[2]=pk2(kb1[0],kb1[1]); u_[3]=pk2(kb1[2],kb1[3]);                  \
        *(uint4v*)&kd_[n_k * KLD + (u_k + 8) * 8] = u_;                      \
        _Pragma("unroll")                                                    \
        for (int i_ = 0; i_ < 4; ++i_) {                                     \
            const int d_ = dq * 4 + i_;                                      \
            uint2v p_;                                                       \
            p_[0] = pk2(va0[i_], va1[i_]);                                   \
            p_[1] = pk2(va2[i_], va3[i_]);                                   \
            const int unit_ = (nq >> 1) ^ vswz;                              \
            *(uint2v*)&vd_[d_ * VTLD + unit_ * 8 + (nq & 1) * 4] = p_;       \
        }                                                                    \
    } while (0)

    // prologue: tile 0 -> buf0, tile 1 -> regs
    LOAD_TILE(0);
    STORE_TILE(0);
    LOAD_TILE(BN);
    __syncthreads();

    // bpermute source-lane addresses (byte = lane*4), constant per thread:
    // srclane = c + 16*(2*(g&1) + (jp>>1))
    const int addr0 = (c + 16 * (2 * (g & 1))) * 4;
    const int addr1 = addr0 + 64;
    const bool hi_half = (g >> 1) != 0;

    for (int t = 0; t < NT; ++t) {
        // stage t+1 into the idle buffer; prefetch t+2 into regs
        if (t + 1 < NT) {
            STORE_TILE((t + 1) & 1);
            if (t + 2 < NT) LOAD_TILE((size_t)(t + 2) * BN);
        }
        const unsigned short* Kb = &K_lds[(t & 1) * KBUF];
        const unsigned short* Vb = &Vt_lds[(t & 1) * VBUF];

        // ---- S = K Q^T (swapped): lane (c,g) gets S[q=c][kv=16ns+4g+r] ----
        f32x4 s[4];
        __builtin_amdgcn_s_setprio(1);
        #pragma unroll
        for (int ns = 0; ns < 4; ++ns) {
            f32x4 tt = {0.f,0.f,0.f,0.f};
            #pragma unroll
            for (int dc = 0; dc < 4; ++dc) {
                ushort8 kf = *(const ushort8*)&Kb[(ns * 16 + c) * KLD + dc * 32 + g * 8];
                tt = __builtin_amdgcn_mfma_f32_16x16x32_bf16(
                        __builtin_bit_cast(bf16x8, kf),
                        __builtin_bit_cast(bf16x8, qf[dc]), tt, 0, 0, 0);
            }
            s[ns] = tt;
        }
        __builtin_amdgcn_s_setprio(0);

        // ---- online softmax (buggy variant), exp2 domain, per-lane row q=c ----
        float mx = s[0][0];
        #pragma unroll
        for (int ns = 0; ns < 4; ++ns)
            #pragma unroll
            for (int r = 0; r < 4; ++r) mx = fmaxf(mx, s[ns][r]);
        mx = fmaxf(mx, __shfl_xor(mx, 16));
        mx = fmaxf(mx, __shfl_xor(mx, 32));
        const float mc = fmaxf(mx, m2);
        float p[4][4];
        float ps = 0.f;
        #pragma unroll
        for (int ns = 0; ns < 4; ++ns)
            #pragma unroll
            for (int r = 0; r < 4; ++r) {
                const float e = exp2f(s[ns][r] - mc);
                p[ns][r] = e;
                ps += e;
            }
        ps += __shfl_xor(ps, 16);
        ps += __shfl_xor(ps, 32);
        const float ln = l_run * exp2f(m2 - mc) + ps;
        m2 = mc;
        l_run = ln;
        const float inv = __builtin_amdgcn_rcpf(ln);

        // ---- pack P/l to bf16 words: wds[ns][rp] = (p[ns][2rp], p[ns][2rp+1]) ----
        unsigned wds[4][2];
        #pragma unroll
        for (int ns = 0; ns < 4; ++ns)
            #pragma unroll
            for (int rp = 0; rp < 2; ++rp)
                wds[ns][rp] = pk2(p[ns][2*rp] * inv, p[ns][2*rp+1] * inv);

        // ---- in-register redistribution to PV A-frags:
        // pa[kp] word jp <- wds[2kp + (g>>1)][jp&1] of lane c + 16*(2(g&1)+(jp>>1))
        uint4v paw0, paw1;
        #pragma unroll
        for (int jp = 0; jp < 4; ++jp) {
            const int adr = (jp >> 1) ? addr1 : addr0;
            const int rp  = jp & 1;
            int x0 = __builtin_amdgcn_ds_bpermute(adr, (int)wds[0][rp]);
            int y0 = __builtin_amdgcn_ds_bpermute(adr, (int)wds[1][rp]);
            int x1 = __builtin_amdgcn_ds_bpermute(adr, (int)wds[2][rp]);
            int y1 = __builtin_amdgcn_ds_bpermute(adr, (int)wds[3][rp]);
            paw0[jp] = (unsigned)(hi_half ? y0 : x0);
            paw1[jp] = (unsigned)(hi_half ? y1 : x1);
        }
        ushort8 pa0 = __builtin_bit_cast(ushort8, paw0);
        ushort8 pa1 = __builtin_bit_cast(ushort8, paw1);

        // ---- PV: B[k = kc*32+g*8+j][d = dt*16+c] from swizzled Vt ----
        __builtin_amdgcn_s_setprio(1);
        #pragma unroll
        for (int dt = 0; dt < 8; ++dt) {
            const int d  = dt * 16 + c;
            const int fz = (d >> 3) & 7;
            ushort8 vb0 = *(const ushort8*)&Vb[d * VTLD + ((0 + g) ^ fz) * 8];
            ushort8 vb1 = *(const ushort8*)&Vb[d * VTLD + ((4 + g) ^ fz) * 8];
            acc[dt] = __builtin_amdgcn_mfma_f32_16x16x32_bf16(
                __builtin_bit_cast(bf16x8, pa0), __builtin_bit_cast(bf16x8, vb0), acc[dt], 0,0,0);
            acc[dt] = __builtin_amdgcn_mfma_f32_16x16x32_bf16(
                __builtin_bit_cast(bf16x8, pa1), __builtin_bit_cast(bf16x8, vb1), acc[dt], 0,0,0);
        }
        __builtin_amdgcn_s_setprio(0);

        __syncthreads();   // tile t reads done everywhere; buf[(t+1)&1] ready
    }

    // ---- epilogue: row = 4g + r = q-row-in-wave, col d = dt*16 + c ----
    float* orow = Og + ((size_t)bh * SQ + qbase + w * 16 + g * 4) * DH + c;
    #pragma unroll
    for (int r = 0; r < 4; ++r) {
        #pragma unroll
        for (int dt = 0; dt < 8; ++dt)
            orow[(size_t)r * DH + dt * 16] = acc[dt][r];
    }
}

extern "C" void kernel_launch(void* const* d_in, const int* in_sizes, int n_in,
                              void* d_out, int out_size, void* d_ws, size_t ws_size,
                              hipStream_t stream) {
    const float* q = (const float*)d_in[0];
    const float* k = (const float*)d_in[1];
    const float* v = (const float*)d_in[2];
    float* o = (float*)d_out;
    dim3 grid(1024);
    fa_fwd_buggy<<<grid, 512, 0, stream>>>(q, k, v, o);
}

// Round 6
// 434.055 us; speedup vs baseline: 4.0786x; 1.0462x over previous
//
#include <hip/hip_runtime.h>
#include <hip/hip_bf16.h>
#include <math.h>

// Buggy flash-attn fwd (no acc rescale, running-l division) per 64-wide KV
// block. B=2 H=16 S=4096 D=128, fp32 in/out, bf16 MFMA compute.
// Round 6: VALU diet, structure frozen vs round 5:
//  - exp2f -> __builtin_amdgcn_exp2f (bare v_exp_f32; args <= 0, flush ok)
//  - bf16 pack -> inline-asm v_cvt_pk_bf16_f32 (guaranteed 1 instr, RNE)
//  - max-reduce written as a tree (fuses to v_max3)

typedef __attribute__((ext_vector_type(8)))  unsigned short ushort8;
typedef __attribute__((ext_vector_type(8)))  __bf16        bf16x8;
typedef __attribute__((ext_vector_type(4)))  float         f32x4;
typedef __attribute__((ext_vector_type(4)))  float         floatv4;
typedef __attribute__((ext_vector_type(2)))  unsigned int  uint2v;
typedef __attribute__((ext_vector_type(4)))  unsigned int  uint4v;

#define SQ   4096
#define SKV  4096
#define DH   128
#define BN   64
#define QB   128
#define NT   (SKV / BN)   // 64
#define KLD  136   // K LDS row stride (bf16 elems): 128 + 8 pad
#define VTLD 72    // Vt row stride: 64 data + 8 pad, 8-unit XOR swizzled
#define KBUF (64 * KLD)
#define VBUF (DH * VTLD)

// packed f32x2 -> bf16x2 word: single v_cvt_pk_bf16_f32 (RNE)
static __device__ __forceinline__ unsigned pk2(float lo, float hi) {
    unsigned r;
    asm("v_cvt_pk_bf16_f32 %0, %1, %2" : "=v"(r) : "v"(lo), "v"(hi));
    return r;
}
// bare v_exp_f32 (exp2); inputs are <= 0 here, underflow->0 desired
static __device__ __forceinline__ float fexp2(float x) {
    return __builtin_amdgcn_exp2f(x);
}

__global__ __launch_bounds__(512, 4) void fa_fwd_buggy(
    const float* __restrict__ Qg, const float* __restrict__ Kg,
    const float* __restrict__ Vg, float* __restrict__ Og)
{
    // LDS: 2 x (K 17.4KB + Vt 18.4KB) = 70KB. Residency is reg-capped at
    // 2 WG/CU, so double-buffering is occupancy-free.
    __shared__ unsigned short K_lds[2 * KBUF];
    __shared__ unsigned short Vt_lds[2 * VBUF];

    const int tid  = threadIdx.x;
    const int w    = tid >> 6;      // wave 0..7, owns q rows w*16..w*16+15
    const int lane = tid & 63;
    const int c    = lane & 15;
    const int g    = lane >> 4;

    // bh->XCD grouping: all 32 qtiles of one bh on one XCD.
    const int wgid  = blockIdx.x;
    const int bh    = (wgid & 7) * 4 + (wgid >> 8);
    const int qtile = (wgid >> 3) & 31;
    const int qbase = qtile * QB;
    // sm_scale * log2(e): QK^T lands directly in exp2 domain.
    const float qscale = 0.08838834764831845f * 1.44269504088896341f;

    // ---- Q fragments (B-operand): n = c = q-row, k = dc*32 + g*8 + j ----
    const float* Qrow = Qg + ((size_t)bh * SQ + qbase + w * 16 + c) * DH;
    ushort8 qf[4];
    #pragma unroll
    for (int dc = 0; dc < 4; ++dc) {
        floatv4 a = *(const floatv4*)(Qrow + dc * 32 + g * 8);
        floatv4 b = *(const floatv4*)(Qrow + dc * 32 + g * 8 + 4);
        uint4v u;
        u[0] = pk2(a[0]*qscale, a[1]*qscale);
        u[1] = pk2(a[2]*qscale, a[3]*qscale);
        u[2] = pk2(b[0]*qscale, b[1]*qscale);
        u[3] = pk2(b[2]*qscale, b[3]*qscale);
        qf[dc] = __builtin_bit_cast(ushort8, u);
    }

    f32x4 acc[8];
    #pragma unroll
    for (int i = 0; i < 8; ++i) { f32x4 z = {0.f,0.f,0.f,0.f}; acc[i] = z; }
    // per-lane running stats for q-row = c (lanes c,c+16,c+32,c+48 duplicate)
    float m2 = -INFINITY;   // log2 domain
    float l_run = 0.f;

    const float* Kbh = Kg + (size_t)bh * SKV * DH;
    const float* Vbh = Vg + (size_t)bh * SKV * DH;

    // staging thread mappings (512 threads)
    const int n_k = tid >> 3;          // K row 0..63
    const int u_k = tid & 7;           // K 8-elem units {u_k, u_k+8}
    const int dq  = tid & 31;          // V d-block (d = 4*dq)
    const int nq  = tid >> 5;          // V n-block 0..15 (n = 4*nq)
    const int vswz = (dq >> 1) & 7;    // (d>>3)&7

    floatv4 ka0, ka1, kb0, kb1;        // K stage regs
    floatv4 va0, va1, va2, va3;        // V stage regs

#define LOAD_TILE(N0) do {                                                   \
        const float* ks_ = Kbh + (size_t)((N0) + n_k) * DH + u_k * 8;        \
        ka0 = *(const floatv4*)(ks_);        ka1 = *(const floatv4*)(ks_+4); \
        kb0 = *(const floatv4*)(ks_ + 64);   kb1 = *(const floatv4*)(ks_+68);\
        const float* vs_ = Vbh + (size_t)((N0) + nq * 4) * DH + dq * 4;      \
        va0 = *(const floatv4*)(vs_);        va1 = *(const floatv4*)(vs_+DH);\
        va2 = *(const floatv4*)(vs_+2*DH);   va3 = *(const floatv4*)(vs_+3*DH);\
    } while (0)

#define STORE_TILE(B) do {                                                   \
        unsigned short* kd_ = &K_lds[(B) * KBUF];                            \
        unsigned short* vd_ = &Vt_lds[(B) * VBUF];                           \
        uint4v u_;                                                           \
        u_[0]=pk2(ka0[0],ka0[1]); u_[1]=pk2(ka0[2],ka0[3]);                  \
        u_[2]=pk2(ka1[0],ka1[1]); u_[3]=pk2(ka1[2],ka1[3]);                  \
        *(uint4v*)&kd_[n_k * KLD + u_k * 8] = u_;                            \
        u_[0]=pk2(kb0[0],kb0[1]); u_[1]=pk2(kb0[2],kb0[3]);                  \
        u_[2]=pk2(kb1[0],kb1[1]); u_[3]=pk2(kb1[2],kb1[3]);                  \
        *(uint4v*)&kd_[n_k * KLD + (u_k + 8) * 8] = u_;                      \
        _Pragma("unroll")                                                    \
        for (int i_ = 0; i_ < 4; ++i_) {                                     \
            const int d_ = dq * 4 + i_;                                      \
            uint2v p_;                                                       \
            p_[0] = pk2(va0[i_], va1[i_]);                                   \
            p_[1] = pk2(va2[i_], va3[i_]);                                   \
            const int unit_ = (nq >> 1) ^ vswz;                              \
            *(uint2v*)&vd_[d_ * VTLD + unit_ * 8 + (nq & 1) * 4] = p_;       \
        }                                                                    \
    } while (0)

    // prologue: tile 0 -> buf0, tile 1 -> regs
    LOAD_TILE(0);
    STORE_TILE(0);
    LOAD_TILE(BN);
    __syncthreads();

    // bpermute source-lane addresses (byte = lane*4), constant per thread:
    // srclane = c + 16*(2*(g&1) + (jp>>1))
    const int addr0 = (c + 16 * (2 * (g & 1))) * 4;
    const int addr1 = addr0 + 64;
    const bool hi_half = (g >> 1) != 0;

    for (int t = 0; t < NT; ++t) {
        // stage t+1 into the idle buffer; prefetch t+2 into regs
        if (t + 1 < NT) {
            STORE_TILE((t + 1) & 1);
            if (t + 2 < NT) LOAD_TILE((size_t)(t + 2) * BN);
        }
        const unsigned short* Kb = &K_lds[(t & 1) * KBUF];
        const unsigned short* Vb = &Vt_lds[(t & 1) * VBUF];

        // ---- S = K Q^T (swapped): lane (c,g) gets S[q=c][kv=16ns+4g+r] ----
        f32x4 s[4];
        __builtin_amdgcn_s_setprio(1);
        #pragma unroll
        for (int ns = 0; ns < 4; ++ns) {
            f32x4 tt = {0.f,0.f,0.f,0.f};
            #pragma unroll
            for (int dc = 0; dc < 4; ++dc) {
                ushort8 kf = *(const ushort8*)&Kb[(ns * 16 + c) * KLD + dc * 32 + g * 8];
                tt = __builtin_amdgcn_mfma_f32_16x16x32_bf16(
                        __builtin_bit_cast(bf16x8, kf),
                        __builtin_bit_cast(bf16x8, qf[dc]), tt, 0, 0, 0);
            }
            s[ns] = tt;
        }
        __builtin_amdgcn_s_setprio(0);

        // ---- online softmax (buggy variant), exp2 domain, per-lane row q=c ----
        // max as a balanced tree (fuses toward v_max3)
        float m01 = fmaxf(fmaxf(s[0][0], s[0][1]), fmaxf(s[0][2], s[0][3]));
        float m23 = fmaxf(fmaxf(s[1][0], s[1][1]), fmaxf(s[1][2], s[1][3]));
        float m45 = fmaxf(fmaxf(s[2][0], s[2][1]), fmaxf(s[2][2], s[2][3]));
        float m67 = fmaxf(fmaxf(s[3][0], s[3][1]), fmaxf(s[3][2], s[3][3]));
        float mx  = fmaxf(fmaxf(m01, m23), fmaxf(m45, m67));
        mx = fmaxf(mx, __shfl_xor(mx, 16));
        mx = fmaxf(mx, __shfl_xor(mx, 32));
        const float mc = fmaxf(mx, m2);
        float p[4][4];
        float ps = 0.f;
        #pragma unroll
        for (int ns = 0; ns < 4; ++ns)
            #pragma unroll
            for (int r = 0; r < 4; ++r) {
                const float e = fexp2(s[ns][r] - mc);
                p[ns][r] = e;
                ps += e;
            }
        ps += __shfl_xor(ps, 16);
        ps += __shfl_xor(ps, 32);
        const float ln = l_run * fexp2(m2 - mc) + ps;
        m2 = mc;
        l_run = ln;
        const float inv = __builtin_amdgcn_rcpf(ln);

        // ---- pack P/l to bf16 words: wds[ns][rp] = (p[ns][2rp], p[ns][2rp+1]) ----
        unsigned wds[4][2];
        #pragma unroll
        for (int ns = 0; ns < 4; ++ns)
            #pragma unroll
            for (int rp = 0; rp < 2; ++rp)
                wds[ns][rp] = pk2(p[ns][2*rp] * inv, p[ns][2*rp+1] * inv);

        // ---- in-register redistribution to PV A-frags:
        // pa[kp] word jp <- wds[2kp + (g>>1)][jp&1] of lane c + 16*(2(g&1)+(jp>>1))
        uint4v paw0, paw1;
        #pragma unroll
        for (int jp = 0; jp < 4; ++jp) {
            const int adr = (jp >> 1) ? addr1 : addr0;
            const int rp  = jp & 1;
            int x0 = __builtin_amdgcn_ds_bpermute(adr, (int)wds[0][rp]);
            int y0 = __builtin_amdgcn_ds_bpermute(adr, (int)wds[1][rp]);
            int x1 = __builtin_amdgcn_ds_bpermute(adr, (int)wds[2][rp]);
            int y1 = __builtin_amdgcn_ds_bpermute(adr, (int)wds[3][rp]);
            paw0[jp] = (unsigned)(hi_half ? y0 : x0);
            paw1[jp] = (unsigned)(hi_half ? y1 : x1);
        }
        ushort8 pa0 = __builtin_bit_cast(ushort8, paw0);
        ushort8 pa1 = __builtin_bit_cast(ushort8, paw1);

        // ---- PV: B[k = kc*32+g*8+j][d = dt*16+c] from swizzled Vt ----
        __builtin_amdgcn_s_setprio(1);
        #pragma unroll
        for (int dt = 0; dt < 8; ++dt) {
            const int d  = dt * 16 + c;
            const int fz = (d >> 3) & 7;
            ushort8 vb0 = *(const ushort8*)&Vb[d * VTLD + ((0 + g) ^ fz) * 8];
            ushort8 vb1 = *(const ushort8*)&Vb[d * VTLD + ((4 + g) ^ fz) * 8];
            acc[dt] = __builtin_amdgcn_mfma_f32_16x16x32_bf16(
                __builtin_bit_cast(bf16x8, pa0), __builtin_bit_cast(bf16x8, vb0), acc[dt], 0,0,0);
            acc[dt] = __builtin_amdgcn_mfma_f32_16x16x32_bf16(
                __builtin_bit_cast(bf16x8, pa1), __builtin_bit_cast(bf16x8, vb1), acc[dt], 0,0,0);
        }
        __builtin_amdgcn_s_setprio(0);

        __syncthreads();   // tile t reads done everywhere; buf[(t+1)&1] ready
    }

    // ---- epilogue: row = 4g + r = q-row-in-wave, col d = dt*16 + c ----
    float* orow = Og + ((size_t)bh * SQ + qbase + w * 16 + g * 4) * DH + c;
    #pragma unroll
    for (int r = 0; r < 4; ++r) {
        #pragma unroll
        for (int dt = 0; dt < 8; ++dt)
            orow[(size_t)r * DH + dt * 16] = acc[dt][r];
    }
}

extern "C" void kernel_launch(void* const* d_in, const int* in_sizes, int n_in,
                              void* d_out, int out_size, void* d_ws, size_t ws_size,
                              hipStream_t stream) {
    const float* q = (const float*)d_in[0];
    const float* k = (const float*)d_in[1];
    const float* v = (const float*)d_in[2];
    float* o = (float*)d_out;
    dim3 grid(1024);
    fa_fwd_buggy<<<grid, 512, 0, stream>>>(q, k, v, o);
}

// Round 8
// 298.832 us; speedup vs baseline: 5.9242x; 1.4525x over previous
//
#include <hip/hip_runtime.h>
#include <hip/hip_bf16.h>
#include <math.h>

// Buggy flash-attn fwd (no acc rescale, running-l division) per 64-wide KV
// block. B=2 H=16 S=4096 D=128, fp32 in/out, bf16 MFMA compute.
// Round 8: round 7 (32x32x16 MFMA, 32 q-rows/wave, m-hat=0 softmax) with the
// ONE isolated bug fixed: P redistribution now uses the two-input
// permlane32_swap (m214 recipe) -- rA = swap(wrd[base], wrd[base+2]) gives
// pw[0]=rA[0] (lo-owner word, dest-h-indexed) and pw[2]=rA[1] (hi-owner word),
// verified lane-by-lane on (c32,h)=(5,0)/(5,1), steps 0/1.

typedef __attribute__((ext_vector_type(8)))  unsigned short ushort8;
typedef __attribute__((ext_vector_type(8)))  __bf16        bf16x8;
typedef __attribute__((ext_vector_type(16))) float         f32x16;
typedef __attribute__((ext_vector_type(4)))  float         floatv4;
typedef __attribute__((ext_vector_type(2)))  unsigned int  uint2v;
typedef __attribute__((ext_vector_type(4)))  unsigned int  uint4v;

#define SQ   4096
#define SKV  4096
#define DH   128
#define BN   64
#define QB   256
#define NT   (SKV / BN)   // 64
#define KLD  136   // K LDS row stride (bf16 elems): 128 + 8 pad
#define VTLD 72    // Vt row stride: 64 data + 8 pad, 8-unit XOR swizzled
#define KBUF (64 * KLD)
#define VBUF (DH * VTLD)

// packed f32x2 -> bf16x2 word: single v_cvt_pk_bf16_f32 (RNE)
static __device__ __forceinline__ unsigned pk2(float lo, float hi) {
    unsigned r;
    asm("v_cvt_pk_bf16_f32 %0, %1, %2" : "=v"(r) : "v"(lo), "v"(hi));
    return r;
}

__global__ __launch_bounds__(512, 2) void fa_fwd_buggy(
    const float* __restrict__ Qg, const float* __restrict__ Kg,
    const float* __restrict__ Vg, float* __restrict__ Og)
{
    // LDS: 2 x (K 17.4KB + Vt 18.4KB) = 70KB; 1 WG/CU (reg-capped).
    __shared__ unsigned short K_lds[2 * KBUF];
    __shared__ unsigned short Vt_lds[2 * VBUF];

    const int tid  = threadIdx.x;
    const int w    = tid >> 6;      // wave 0..7, owns q rows w*32..w*32+31
    const int lane = tid & 63;
    const int c32  = lane & 31;
    const int h    = lane >> 5;     // k-half within fragments

    // bh->XCD grouping: 4 bh per XCD, streamed.
    const int wgid  = blockIdx.x;            // 0..511
    const int bh    = (wgid & 7) * 4 + (wgid >> 7);
    const int qtile = (wgid >> 3) & 15;
    const int qbase = qtile * QB;
    // sm_scale * log2(e): QK^T lands directly in exp2 domain.
    const float qscale = 0.08838834764831845f * 1.44269504088896341f;

    // ---- Q fragments (B-operand of swapped QK): col n = c32 = q-row,
    // k = ds*16 + h*8 + j ----
    const float* Qrow = Qg + ((size_t)bh * SQ + qbase + w * 32 + c32) * DH;
    ushort8 qf[8];
    #pragma unroll
    for (int ds = 0; ds < 8; ++ds) {
        floatv4 a = *(const floatv4*)(Qrow + ds * 16 + h * 8);
        floatv4 b = *(const floatv4*)(Qrow + ds * 16 + h * 8 + 4);
        uint4v u;
        u[0] = pk2(a[0]*qscale, a[1]*qscale);
        u[1] = pk2(a[2]*qscale, a[3]*qscale);
        u[2] = pk2(b[0]*qscale, b[1]*qscale);
        u[3] = pk2(b[2]*qscale, b[3]*qscale);
        qf[ds] = __builtin_bit_cast(ushort8, u);
    }

    f32x16 acc[4];
    #pragma unroll
    for (int i = 0; i < 4; ++i)
        #pragma unroll
        for (int r = 0; r < 16; ++r) acc[i][r] = 0.f;

    float l_run = 0.f;   // running denominator, m-hat = 0 domain

    const float* Kbh = Kg + (size_t)bh * SKV * DH;
    const float* Vbh = Vg + (size_t)bh * SKV * DH;

    // staging thread mappings (512 threads) — identical to rounds 4-6
    const int n_k = tid >> 3;          // K row 0..63
    const int u_k = tid & 7;           // K 8-elem units {u_k, u_k+8}
    const int dq  = tid & 31;          // V d-block (d = 4*dq)
    const int nq  = tid >> 5;          // V n-block 0..15 (n = 4*nq)
    const int vswz = (dq >> 1) & 7;    // (d>>3)&7

    floatv4 ka0, ka1, kb0, kb1;        // K stage regs
    floatv4 va0, va1, va2, va3;        // V stage regs

#define LOAD_TILE(N0) do {                                                   \
        const float* ks_ = Kbh + (size_t)((N0) + n_k) * DH + u_k * 8;        \
        ka0 = *(const floatv4*)(ks_);        ka1 = *(const floatv4*)(ks_+4); \
        kb0 = *(const floatv4*)(ks_ + 64);   kb1 = *(const floatv4*)(ks_+68);\
        const float* vs_ = Vbh + (size_t)((N0) + nq * 4) * DH + dq * 4;      \
        va0 = *(const floatv4*)(vs_);        va1 = *(const floatv4*)(vs_+DH);\
        va2 = *(const floatv4*)(vs_+2*DH);   va3 = *(const floatv4*)(vs_+3*DH);\
    } while (0)

#define STORE_TILE(B) do {                                                   \
        unsigned short* kd_ = &K_lds[(B) * KBUF];                            \
        unsigned short* vd_ = &Vt_lds[(B) * VBUF];                           \
        uint4v u_;                                                           \
        u_[0]=pk2(ka0[0],ka0[1]); u_[1]=pk2(ka0[2],ka0[3]);                  \
        u_[2]=pk2(ka1[0],ka1[1]); u_[3]=pk2(ka1[2],ka1[3]);                  \
        *(uint4v*)&kd_[n_k * KLD + u_k * 8] = u_;                            \
        u_[0]=pk2(kb0[0],kb0[1]); u_[1]=pk2(kb0[2],kb0[3]);                  \
        u_[2]=pk2(kb1[0],kb1[1]); u_[3]=pk2(kb1[2],kb1[3]);                  \
        *(uint4v*)&kd_[n_k * KLD + (u_k + 8) * 8] = u_;                      \
        _Pragma("unroll")                                                    \
        for (int i_ = 0; i_ < 4; ++i_) {                                     \
            const int d_ = dq * 4 + i_;                                      \
            uint2v p_;                                                       \
            p_[0] = pk2(va0[i_], va1[i_]);                                   \
            p_[1] = pk2(va2[i_], va3[i_]);                                   \
            const int unit_ = (nq >> 1) ^ vswz;                              \
            *(uint2v*)&vd_[d_ * VTLD + unit_ * 8 + (nq & 1) * 4] = p_;       \
        }                                                                    \
    } while (0)

    // prologue: tile 0 -> buf0, tile 1 -> regs
    LOAD_TILE(0);
    STORE_TILE(0);
    LOAD_TILE(BN);
    __syncthreads();

    for (int t = 0; t < NT; ++t) {
        // stage t+1 into the idle buffer; prefetch t+2 into regs
        if (t + 1 < NT) {
            STORE_TILE((t + 1) & 1);
            if (t + 2 < NT) LOAD_TILE((size_t)(t + 2) * BN);
        }
        const unsigned short* Kb = &K_lds[(t & 1) * KBUF];
        const unsigned short* Vb = &Vt_lds[(t & 1) * VBUF];

        // ---- S = K Q^T (swapped, 32x32x16): C col = c32 = q,
        // row kv = ns*32 + (r&3)+8*(r>>2)+4*h  [verified m74/m101 layout] ----
        f32x16 s[2];
        __builtin_amdgcn_s_setprio(1);
        #pragma unroll
        for (int ns = 0; ns < 2; ++ns) {
            f32x16 tt;
            #pragma unroll
            for (int r = 0; r < 16; ++r) tt[r] = 0.f;
            #pragma unroll
            for (int ds = 0; ds < 8; ++ds) {
                ushort8 kf = *(const ushort8*)&Kb[(ns * 32 + c32) * KLD + ds * 16 + h * 8];
                tt = __builtin_amdgcn_mfma_f32_32x32x16_bf16(
                        __builtin_bit_cast(bf16x8, kf),
                        __builtin_bit_cast(bf16x8, qf[ds]), tt, 0, 0, 0);
            }
            s[ns] = tt;
        }
        __builtin_amdgcn_s_setprio(0);

        // ---- softmax, buggy variant, m-hat = 0 (p/l invariant to max) ----
        float ps = 0.f;
        #pragma unroll
        for (int ns = 0; ns < 2; ++ns) {
            #pragma unroll
            for (int r = 0; r < 16; ++r)
                s[ns][r] = __builtin_amdgcn_exp2f(s[ns][r]);
            float q0 = (s[ns][0]  + s[ns][1])  + (s[ns][2]  + s[ns][3]);
            float q1 = (s[ns][4]  + s[ns][5])  + (s[ns][6]  + s[ns][7]);
            float q2 = (s[ns][8]  + s[ns][9])  + (s[ns][10] + s[ns][11]);
            float q3 = (s[ns][12] + s[ns][13]) + (s[ns][14] + s[ns][15]);
            ps += (q0 + q1) + (q2 + q3);
        }
        ps += __shfl_xor(ps, 32);          // combine the two k-halves
        const float ln = l_run + ps;
        l_run = ln;
        const float inv = __builtin_amdgcn_rcpf(ln);

        // ---- pack P/l to bf16 words: wrd[ns][i] covers kv pair
        // {8*(i>>1) + 2*(i&1) + 4*h_owner, +1} within tile ns ----
        unsigned wrd[2][8];
        #pragma unroll
        for (int ns = 0; ns < 2; ++ns)
            #pragma unroll
            for (int i = 0; i < 8; ++i)
                wrd[ns][i] = pk2(s[ns][2*i] * inv, s[ns][2*i+1] * inv);

        // ---- redistribute to PV A-frags via two-input permlane32_swap:
        // dest (c32,h) word jp needs owner-half (jp>>1)'s wrd[4(step&1)+2h+(jp&1)].
        // rA = swap(wrd[base], wrd[base+2]):
        //   rA[0] (new vdst): lo lanes keep wrd[base] (their 2h=0 word),
        //                     hi lanes get lo-owner's wrd[base+2] (their 2h=2 word)
        //   rA[1] (new vsrc): lo lanes get hi-owner's wrd[base],
        //                     hi lanes keep own wrd[base+2]
        // -> rA[0] = pw[0], rA[1] = pw[2]; rB likewise for odd words. ----
        ushort8 pa[4];
        #pragma unroll
        for (int step = 0; step < 4; ++step) {
            const int ns   = step >> 1;
            const int base = 4 * (step & 1);
            auto rA = __builtin_amdgcn_permlane32_swap(
                          (int)wrd[ns][base + 0], (int)wrd[ns][base + 2], false, false);
            auto rB = __builtin_amdgcn_permlane32_swap(
                          (int)wrd[ns][base + 1], (int)wrd[ns][base + 3], false, false);
            uint4v pw;
            pw[0] = (unsigned)rA[0];   // j0,1 : kv 16*step + 8h + {0,1}
            pw[1] = (unsigned)rB[0];   // j2,3 : kv + {2,3}
            pw[2] = (unsigned)rA[1];   // j4,5 : kv + {4,5}
            pw[3] = (unsigned)rB[1];   // j6,7 : kv + {6,7}
            pa[step] = __builtin_bit_cast(ushort8, pw);
        }

        // ---- PV (32x32x16): A = P (32q x 16kv), B = V (16kv x 32d);
        // B col = c32 = d, k = 16*step + 8*h + j from swizzled Vt ----
        __builtin_amdgcn_s_setprio(1);
        #pragma unroll
        for (int dt = 0; dt < 4; ++dt) {
            const int d  = dt * 32 + c32;
            const int fz = (d >> 3) & 7;
            #pragma unroll
            for (int step = 0; step < 4; ++step) {
                ushort8 vb = *(const ushort8*)&Vb[d * VTLD + (((2*step + h) ^ fz) * 8)];
                acc[dt] = __builtin_amdgcn_mfma_f32_32x32x16_bf16(
                    __builtin_bit_cast(bf16x8, pa[step]),
                    __builtin_bit_cast(bf16x8, vb), acc[dt], 0, 0, 0);
            }
        }
        __builtin_amdgcn_s_setprio(0);

        __syncthreads();   // tile t reads done everywhere; buf[(t+1)&1] ready
    }

    // ---- epilogue: PV C layout: col = c32 = d-local,
    // row q_local = (r&3) + 8*(r>>2) + 4*h ----
    float* ob = Og + ((size_t)bh * SQ + qbase + w * 32) * DH + c32;
    #pragma unroll
    for (int dt = 0; dt < 4; ++dt) {
        #pragma unroll
        for (int r = 0; r < 16; ++r) {
            const int qrow = (r & 3) + 8 * (r >> 2) + 4 * h;
            ob[(size_t)qrow * DH + dt * 32] = acc[dt][r];
        }
    }
}

extern "C" void kernel_launch(void* const* d_in, const int* in_sizes, int n_in,
                              void* d_out, int out_size, void* d_ws, size_t ws_size,
                              hipStream_t stream) {
    const float* q = (const float*)d_in[0];
    const float* k = (const float*)d_in[1];
    const float* v = (const float*)d_in[2];
    float* o = (float*)d_out;
    dim3 grid((SQ / QB) * 32);   // 512 WGs
    fa_fwd_buggy<<<grid, 512, 0, stream>>>(q, k, v, o);
}

// Round 9
// 296.612 us; speedup vs baseline: 5.9686x; 1.0075x over previous
//
#include <hip/hip_runtime.h>
#include <hip/hip_bf16.h>
#include <math.h>

// Buggy flash-attn fwd (no acc rescale, running-l division) per 64-wide KV
// block. B=2 H=16 S=4096 D=128, fp32 in/out, bf16 MFMA compute.
// Round 9: T15 double-pipeline -- QK(t+1) MFMAs overlap softmax(t) VALU
// (independent register streams), PV(t) last. K double-buffered, V TRIPLE-
// buffered (epoch analysis: PV(t) reads V[t%3] while STORE(t+2) writes
// V[(t+2)%3] in the same barrier epoch). sA/sB ping-pong via x2-unrolled
// body (static reg indexing). All layouts bit-identical to round 8.

typedef __attribute__((ext_vector_type(8)))  unsigned short ushort8;
typedef __attribute__((ext_vector_type(8)))  __bf16        bf16x8;
typedef __attribute__((ext_vector_type(16))) float         f32x16;
typedef __attribute__((ext_vector_type(4)))  float         floatv4;
typedef __attribute__((ext_vector_type(2)))  unsigned int  uint2v;
typedef __attribute__((ext_vector_type(4)))  unsigned int  uint4v;

#define SQ   4096
#define SKV  4096
#define DH   128
#define BN   64
#define QB   256
#define NT   (SKV / BN)   // 64
#define KLD  136   // K LDS row stride (bf16 elems): 128 + 8 pad
#define VTLD 72    // Vt row stride: 64 data + 8 pad, 8-unit XOR swizzled
#define KBUF (64 * KLD)
#define VBUF (DH * VTLD)

// packed f32x2 -> bf16x2 word: single v_cvt_pk_bf16_f32 (RNE)
static __device__ __forceinline__ unsigned pk2(float lo, float hi) {
    unsigned r;
    asm("v_cvt_pk_bf16_f32 %0, %1, %2" : "=v"(r) : "v"(lo), "v"(hi));
    return r;
}

__global__ __launch_bounds__(512, 2) void fa_fwd_buggy(
    const float* __restrict__ Qg, const float* __restrict__ Kg,
    const float* __restrict__ Vg, float* __restrict__ Og)
{
    // LDS: K 2x17.4KB + Vt 3x18.4KB = 89KB; 1 WG/CU (reg-capped anyway).
    __shared__ unsigned short K_lds[2 * KBUF];
    __shared__ unsigned short Vt_lds[3 * VBUF];

    const int tid  = threadIdx.x;
    const int w    = tid >> 6;      // wave 0..7, owns q rows w*32..w*32+31
    const int lane = tid & 63;
    const int c32  = lane & 31;
    const int h    = lane >> 5;     // k-half within fragments

    // bh->XCD grouping: 4 bh per XCD, streamed.
    const int wgid  = blockIdx.x;            // 0..511
    const int bh    = (wgid & 7) * 4 + (wgid >> 7);
    const int qtile = (wgid >> 3) & 15;
    const int qbase = qtile * QB;
    const float qscale = 0.08838834764831845f * 1.44269504088896341f;

    // ---- Q fragments (B-operand of swapped QK): col n = c32 = q-row,
    // k = ds*16 + h*8 + j ----
    const float* Qrow = Qg + ((size_t)bh * SQ + qbase + w * 32 + c32) * DH;
    ushort8 qf[8];
    #pragma unroll
    for (int ds = 0; ds < 8; ++ds) {
        floatv4 a = *(const floatv4*)(Qrow + ds * 16 + h * 8);
        floatv4 b = *(const floatv4*)(Qrow + ds * 16 + h * 8 + 4);
        uint4v u;
        u[0] = pk2(a[0]*qscale, a[1]*qscale);
        u[1] = pk2(a[2]*qscale, a[3]*qscale);
        u[2] = pk2(b[0]*qscale, b[1]*qscale);
        u[3] = pk2(b[2]*qscale, b[3]*qscale);
        qf[ds] = __builtin_bit_cast(ushort8, u);
    }

    f32x16 acc[4];
    #pragma unroll
    for (int i = 0; i < 4; ++i)
        #pragma unroll
        for (int r = 0; r < 16; ++r) acc[i][r] = 0.f;

    float l_run = 0.f;   // running denominator, m-hat = 0 domain

    const float* Kbh = Kg + (size_t)bh * SKV * DH;
    const float* Vbh = Vg + (size_t)bh * SKV * DH;

    // staging thread mappings (512 threads) — identical to rounds 4-8
    const int n_k = tid >> 3;          // K row 0..63
    const int u_k = tid & 7;           // K 8-elem units {u_k, u_k+8}
    const int dq  = tid & 31;          // V d-block (d = 4*dq)
    const int nq  = tid >> 5;          // V n-block 0..15 (n = 4*nq)
    const int vswz = (dq >> 1) & 7;    // (d>>3)&7

    floatv4 ka0, ka1, kb0, kb1;        // K stage regs
    floatv4 va0, va1, va2, va3;        // V stage regs

#define LOAD_TILE(N0) do {                                                   \
        const float* ks_ = Kbh + (size_t)((N0) + n_k) * DH + u_k * 8;        \
        ka0 = *(const floatv4*)(ks_);        ka1 = *(const floatv4*)(ks_+4); \
        kb0 = *(const floatv4*)(ks_ + 64);   kb1 = *(const floatv4*)(ks_+68);\
        const float* vs_ = Vbh + (size_t)((N0) + nq * 4) * DH + dq * 4;      \
        va0 = *(const floatv4*)(vs_);        va1 = *(const floatv4*)(vs_+DH);\
        va2 = *(const floatv4*)(vs_+2*DH);   va3 = *(const floatv4*)(vs_+3*DH);\
    } while (0)

#define STORE_TILE(KS, VS) do {                                              \
        unsigned short* kd_ = &K_lds[(KS) * KBUF];                           \
        unsigned short* vd_ = &Vt_lds[(VS) * VBUF];                          \
        uint4v u_;                                                           \
        u_[0]=pk2(ka0[0],ka0[1]); u_[1]=pk2(ka0[2],ka0[3]);                  \
        u_[2]=pk2(ka1[0],ka1[1]); u_[3]=pk2(ka1[2],ka1[3]);                  \
        *(uint4v*)&kd_[n_k * KLD + u_k * 8] = u_;                            \
        u_[0]=pk2(kb0[0],kb0[1]); u_[1]=pk2(kb0[2],kb0[3]);                  \
        u_[2]=pk2(kb1[0],kb1[1]); u_[3]=pk2(kb1[2],kb1[3]);                  \
        *(uint4v*)&kd_[n_k * KLD + (u_k + 8) * 8] = u_;                      \
        _Pragma("unroll")                                                    \
        for (int i_ = 0; i_ < 4; ++i_) {                                     \
            const int d_ = dq * 4 + i_;                                      \
            uint2v p_;                                                       \
            p_[0] = pk2(va0[i_], va1[i_]);                                   \
            p_[1] = pk2(va2[i_], va3[i_]);                                   \
            const int unit_ = (nq >> 1) ^ vswz;                              \
            *(uint2v*)&vd_[d_ * VTLD + unit_ * 8 + (nq & 1) * 4] = p_;       \
        }                                                                    \
    } while (0)

// QK for one tile into named S0,S1 (C: col=c32=q, row kv=(r&3)+8(r>>2)+4h)
#define QK_TILE(S0, S1, KS) do {                                             \
        const unsigned short* kb_ = &K_lds[(KS) * KBUF];                     \
        f32x16 t0_, t1_;                                                     \
        _Pragma("unroll")                                                    \
        for (int r_ = 0; r_ < 16; ++r_) { t0_[r_] = 0.f; t1_[r_] = 0.f; }    \
        __builtin_amdgcn_s_setprio(1);                                       \
        _Pragma("unroll")                                                    \
        for (int ds_ = 0; ds_ < 8; ++ds_) {                                  \
            ushort8 kf0_ = *(const ushort8*)&kb_[(c32)      * KLD + ds_*16 + h*8]; \
            ushort8 kf1_ = *(const ushort8*)&kb_[(32 + c32) * KLD + ds_*16 + h*8]; \
            t0_ = __builtin_amdgcn_mfma_f32_32x32x16_bf16(                   \
                    __builtin_bit_cast(bf16x8, kf0_),                        \
                    __builtin_bit_cast(bf16x8, qf[ds_]), t0_, 0, 0, 0);      \
            t1_ = __builtin_amdgcn_mfma_f32_32x32x16_bf16(                   \
                    __builtin_bit_cast(bf16x8, kf1_),                        \
                    __builtin_bit_cast(bf16x8, qf[ds_]), t1_, 0, 0, 0);      \
        }                                                                    \
        __builtin_amdgcn_s_setprio(0);                                       \
        S0 = t0_; S1 = t1_;                                                  \
    } while (0)

// softmax (m-hat=0, buggy running-l) + pack + permlane redistribution -> pa[4]
#define SM_PACK(S0, S1, PA) do {                                             \
        float ps_ = 0.f;                                                     \
        _Pragma("unroll")                                                    \
        for (int r_ = 0; r_ < 16; ++r_) S0[r_] = __builtin_amdgcn_exp2f(S0[r_]); \
        _Pragma("unroll")                                                    \
        for (int r_ = 0; r_ < 16; ++r_) S1[r_] = __builtin_amdgcn_exp2f(S1[r_]); \
        {                                                                    \
            float q0_ = (S0[0]+S0[1])+(S0[2]+S0[3]);                         \
            float q1_ = (S0[4]+S0[5])+(S0[6]+S0[7]);                         \
            float q2_ = (S0[8]+S0[9])+(S0[10]+S0[11]);                       \
            float q3_ = (S0[12]+S0[13])+(S0[14]+S0[15]);                     \
            float q4_ = (S1[0]+S1[1])+(S1[2]+S1[3]);                         \
            float q5_ = (S1[4]+S1[5])+(S1[6]+S1[7]);                         \
            float q6_ = (S1[8]+S1[9])+(S1[10]+S1[11]);                       \
            float q7_ = (S1[12]+S1[13])+(S1[14]+S1[15]);                     \
            ps_ = ((q0_+q1_)+(q2_+q3_)) + ((q4_+q5_)+(q6_+q7_));             \
        }                                                                    \
        ps_ += __shfl_xor(ps_, 32);                                          \
        const float ln_ = l_run + ps_;                                       \
        l_run = ln_;                                                         \
        const float inv_ = __builtin_amdgcn_rcpf(ln_);                       \
        unsigned wrd_[2][8];                                                 \
        _Pragma("unroll")                                                    \
        for (int i_ = 0; i_ < 8; ++i_)                                       \
            wrd_[0][i_] = pk2(S0[2*i_] * inv_, S0[2*i_+1] * inv_);           \
        _Pragma("unroll")                                                    \
        for (int i_ = 0; i_ < 8; ++i_)                                       \
            wrd_[1][i_] = pk2(S1[2*i_] * inv_, S1[2*i_+1] * inv_);           \
        _Pragma("unroll")                                                    \
        for (int st_ = 0; st_ < 4; ++st_) {                                  \
            const int ns_   = st_ >> 1;                                      \
            const int base_ = 4 * (st_ & 1);                                 \
            auto rA_ = __builtin_amdgcn_permlane32_swap(                     \
                          (int)wrd_[ns_][base_ + 0], (int)wrd_[ns_][base_ + 2], false, false); \
            auto rB_ = __builtin_amdgcn_permlane32_swap(                     \
                          (int)wrd_[ns_][base_ + 1], (int)wrd_[ns_][base_ + 3], false, false); \
            uint4v pw_;                                                      \
            pw_[0] = (unsigned)rA_[0];                                       \
            pw_[1] = (unsigned)rB_[0];                                       \
            pw_[2] = (unsigned)rA_[1];                                       \
            pw_[3] = (unsigned)rB_[1];                                       \
            PA[st_] = __builtin_bit_cast(ushort8, pw_);                      \
        }                                                                    \
    } while (0)

// PV: A = PA (32q x 16kv), B = V (16kv x 32d) from swizzled Vt slot VS
#define PV_TILE(PA, VS) do {                                                 \
        const unsigned short* vb_ = &Vt_lds[(VS) * VBUF];                    \
        __builtin_amdgcn_s_setprio(1);                                       \
        _Pragma("unroll")                                                    \
        for (int dt_ = 0; dt_ < 4; ++dt_) {                                  \
            const int d_  = dt_ * 32 + c32;                                  \
            const int fz_ = (d_ >> 3) & 7;                                   \
            _Pragma("unroll")                                                \
            for (int st_ = 0; st_ < 4; ++st_) {                              \
                ushort8 vv_ = *(const ushort8*)&vb_[d_ * VTLD + (((2*st_ + h) ^ fz_) * 8)]; \
                acc[dt_] = __builtin_amdgcn_mfma_f32_32x32x16_bf16(          \
                    __builtin_bit_cast(bf16x8, PA[st_]),                     \
                    __builtin_bit_cast(bf16x8, vv_), acc[dt_], 0, 0, 0);     \
            }                                                                \
        }                                                                    \
        __builtin_amdgcn_s_setprio(0);                                       \
    } while (0)

    // prologue: tile 0 -> K0/V0, tile 1 -> regs, QK(0) -> sA
    LOAD_TILE(0);
    STORE_TILE(0, 0);
    LOAD_TILE(BN);
    __syncthreads();

    f32x16 sA0, sA1, sB0, sB1;
    QK_TILE(sA0, sA1, 0);

    int vs0 = 0;  // t % 3 at loop top
    for (int t = 0; t < NT; t += 2) {
        const int vs1 = (vs0 == 2) ? 0 : vs0 + 1;   // (t+1) % 3
        const int vs2 = (vs1 == 2) ? 0 : vs1 + 1;   // (t+2) % 3

        // ---- phase even: tile t (scores in sA), QK(t+1) overlaps sm(t) ----
        STORE_TILE(1, vs1);                         // tile t+1 -> K1, V[vs1]
        if (t + 2 < NT) LOAD_TILE((size_t)(t + 2) * BN);
        __syncthreads();
        QK_TILE(sB0, sB1, 1);                       // MFMA stream (indep of sA)
        {
            ushort8 pa[4];
            SM_PACK(sA0, sA1, pa);                  // VALU stream
            PV_TILE(pa, vs0);
        }

        // ---- phase odd: tile t+1 (scores in sB) ----
        if (t + 2 < NT) {
            STORE_TILE(0, vs2);                     // tile t+2 -> K0, V[vs2]
            if (t + 3 < NT) LOAD_TILE((size_t)(t + 3) * BN);
        }
        __syncthreads();
        if (t + 2 < NT) QK_TILE(sA0, sA1, 0);       // QK(t+2) -> sA
        {
            ushort8 pa[4];
            SM_PACK(sB0, sB1, pa);
            PV_TILE(pa, vs1);
        }

        vs0 = vs2;
    }

    // ---- epilogue: PV C layout: col = c32 = d-local,
    // row q_local = (r&3) + 8*(r>>2) + 4*h ----
    float* ob = Og + ((size_t)bh * SQ + qbase + w * 32) * DH + c32;
    #pragma unroll
    for (int dt = 0; dt < 4; ++dt) {
        #pragma unroll
        for (int r = 0; r < 16; ++r) {
            const int qrow = (r & 3) + 8 * (r >> 2) + 4 * h;
            ob[(size_t)qrow * DH + dt * 32] = acc[dt][r];
        }
    }
}

extern "C" void kernel_launch(void* const* d_in, const int* in_sizes, int n_in,
                              void* d_out, int out_size, void* d_ws, size_t ws_size,
                              hipStream_t stream) {
    const float* q = (const float*)d_in[0];
    const float* k = (const float*)d_in[1];
    const float* v = (const float*)d_in[2];
    float* o = (float*)d_out;
    dim3 grid((SQ / QB) * 32);   // 512 WGs
    fa_fwd_buggy<<<grid, 512, 0, stream>>>(q, k, v, o);
}